// Round 8
// baseline (188.135 us; speedup 1.0000x reference)
//
#include <hip/hip_runtime.h>
#include <hip/hip_bf16.h>

// Problem constants (P=1 folded out everywhere)
#define NB   8      // batch
#define NA   8      // actions
#define ND   8      // dim_qk
#define NCH  64     // NA*ND q/k channels
#define GT   32     // grid T=H=W
#define KREG 216    // 6^3 halo voxels
#define IMS  40     // im2col row stride in halfwords (80 B, 16B-aligned)

typedef _Float16 h2_t  __attribute__((ext_vector_type(2)));
typedef _Float16 f16x8 __attribute__((ext_vector_type(8)));
typedef float    f32x4 __attribute__((ext_vector_type(4)));

static __device__ __forceinline__ unsigned pack_h2(float a, float b) {
#if __has_builtin(__builtin_amdgcn_cvt_pkrtz)
    return __builtin_bit_cast(unsigned, __builtin_amdgcn_cvt_pkrtz(a, b));
#else
    unsigned short ha = __builtin_bit_cast(unsigned short, (_Float16)a);
    unsigned short hb = __builtin_bit_cast(unsigned short, (_Float16)b);
    return (unsigned)ha | ((unsigned)hb << 16);
#endif
}

static __device__ __forceinline__ float dot2(unsigned k, unsigned q, float c) {
#if __has_builtin(__builtin_amdgcn_fdot2)
    return __builtin_amdgcn_fdot2(__builtin_bit_cast(h2_t, k),
                                  __builtin_bit_cast(h2_t, q), c, false);
#else
    h2_t a = __builtin_bit_cast(h2_t, k), b = __builtin_bit_cast(h2_t, q);
    return c + (float)a[0] * (float)b[0] + (float)a[1] * (float)b[1];
#endif
}

// Single fused kernel, one LDS pool with lifetime overlays:
//   build window:  xS[0,2048) BTS[2048,11264) imc[11264,29184) cim[29184,34304)
//   attn  window:  kvS[0,31104) qS[31104,40320)   (barrier-separated)
// GEMM1 (MFMA 16x16x32_f16): [k 64ch + v 8ch] x 224 halo-vox -> kvS rows.
// GEMM2: [q 64ch] x 64 center-vox -> qS rows (replaces 432 scalar FMAs/thread).
// Phase C: qp = 1 b128 read; sims via v_dot2; softmax; v via b128 unit read.
__launch_bounds__(256, 4)
__global__ void avi_kernel(const float* __restrict__ values,
                           const float* __restrict__ rewards,
                           const float* __restrict__ w_qk,
                           const float* __restrict__ w_v,
                           float* __restrict__ out) {
    __shared__ __align__(16) char uS[40320];
    float*    xS  = (float*)uS;                 // [512] 8^3 x tile, origin g0-2
    _Float16* BTS = (_Float16*)(uS + 2048);     // [144][32]: 0..63 k, 64..71 v,
                                                //   72..79 zero, 80..143 q
    _Float16* imc = (_Float16*)(uS + 11264);    // [224][IMS] halo im2col
    _Float16* cim = (_Float16*)(uS + 29184);    // [64][IMS] center im2col
    char*     kvS = uS;                         // [216][144B] k/v rows
    char*     qS  = uS + 31104;                 // [64][144B] q rows (+pad=outP)

    const int tid  = threadIdx.x;
    const int bb   = blockIdx.x >> 9;      // batch
    const int tile = blockIdx.x & 511;     // 8x8x8 tiles of 4^3
    const int tz = tile >> 6, ty = (tile >> 3) & 7, tx = tile & 7;
    const int g0z = tz * 4, g0y = ty * 4, g0x = tx * 4;
    const int base_in = bb * (GT * GT * GT);

    // ---- Phase A: x staging + BTS build ----
    for (int i = tid; i < 512; i += 256) {
        int lz = i >> 6, ly = (i >> 3) & 7, lx = i & 7;
        int gz = g0z + lz - 2, gy = g0y + ly - 2, gx = g0x + lx - 2;
        float v = 0.f;
        if ((unsigned)gz < 32u && (unsigned)gy < 32u && (unsigned)gx < 32u) {
            int idx = base_in + gz * 1024 + gy * 32 + gx;
            v = values[idx] + rewards[idx];
        }
        xS[i] = v;
    }
    // zero pads: cols 27..31 all 144 rows (720) + rows 72..79 cols 0..26 (216)
    for (int i = tid; i < 936; i += 256) {
        int row, col;
        if (i < 720) { row = i / 5; col = 27 + (i % 5); }
        else         { int j = i - 720; row = 72 + j / 27; col = j % 27; }
        BTS[row * 32 + col] = (_Float16)0.f;
    }
    // k rows 0..63 <- w_qk rows 64..127
    for (int i = tid; i < 1728; i += 256) {
        int n = i / 27, k = i - n * 27;
        BTS[n * 32 + k] = (_Float16)w_qk[(NCH + n) * 27 + k];
    }
    // q rows 80..143 <- w_qk rows 0..63
    for (int i = tid; i < 1728; i += 256) {
        int n = i / 27, k = i - n * 27;
        BTS[(80 + n) * 32 + k] = (_Float16)w_qk[n * 27 + k];
    }
    // v rows 64..71 <- softmax(w_v)
    if (tid < NA) {
        float r[27], m = -1e30f;
        #pragma unroll
        for (int j = 0; j < 27; ++j) { r[j] = w_v[tid * 27 + j]; m = fmaxf(m, r[j]); }
        float s = 0.f;
        #pragma unroll
        for (int j = 0; j < 27; ++j) { r[j] = __expf(r[j] - m); s += r[j]; }
        float inv = 1.f / s;
        #pragma unroll
        for (int j = 0; j < 27; ++j)
            BTS[(64 + tid) * 32 + j] = (_Float16)(r[j] * inv);
    }
    __syncthreads();

    // ---- Phase B1: halo im2col (tid<224) + center im2col (tid>=224) ----
    if (tid < 224) {
        unsigned rowU[16];
        if (tid < KREG) {
            int vz = tid / 36, rem = tid - vz * 36, vy = rem / 6, vx = rem - vy * 6;
            int gz = g0z + vz - 1, gy = g0y + vy - 1, gx = g0x + vx - 1;
            float mask = ((unsigned)gz < 32u && (unsigned)gy < 32u && (unsigned)gx < 32u)
                             ? 1.f : 0.f;
            float xr[27];
            #pragma unroll
            for (int t = 0; t < 27; ++t) {
                int dz = t / 9, dy = (t / 3) % 3, dx = t % 3;
                xr[t] = xS[(vz + dz) * 64 + (vy + dy) * 8 + (vx + dx)] * mask;
            }
            #pragma unroll
            for (int p = 0; p < 13; ++p) rowU[p] = pack_h2(xr[2 * p], xr[2 * p + 1]);
            rowU[13] = pack_h2(xr[26], 0.f);
            rowU[14] = rowU[15] = 0u;
        } else {
            #pragma unroll
            for (int p = 0; p < 16; ++p) rowU[p] = 0u;
        }
        int4* dst = (int4*)((char*)imc + tid * (IMS * 2));
        dst[0] = make_int4(rowU[0], rowU[1], rowU[2], rowU[3]);
        dst[1] = make_int4(rowU[4], rowU[5], rowU[6], rowU[7]);
        dst[2] = make_int4(rowU[8], rowU[9], rowU[10], rowU[11]);
        dst[3] = make_int4(rowU[12], rowU[13], rowU[14], rowU[15]);
    } else {
        for (int rr = tid - 224; rr < 64; rr += 32) {
            int lz = rr >> 4, ly = (rr >> 2) & 3, lx = rr & 3;
            float xr[27];
            #pragma unroll
            for (int t = 0; t < 27; ++t) {
                int dz = t / 9, dy = (t / 3) % 3, dx = t % 3;
                xr[t] = xS[(lz + 1 + dz) * 64 + (ly + 1 + dy) * 8 + (lx + 1 + dx)];
            }
            unsigned rowU[16];
            #pragma unroll
            for (int p = 0; p < 13; ++p) rowU[p] = pack_h2(xr[2 * p], xr[2 * p + 1]);
            rowU[13] = pack_h2(xr[26], 0.f);
            rowU[14] = rowU[15] = 0u;
            int4* dst = (int4*)((char*)cim + rr * (IMS * 2));
            dst[0] = make_int4(rowU[0], rowU[1], rowU[2], rowU[3]);
            dst[1] = make_int4(rowU[4], rowU[5], rowU[6], rowU[7]);
            dst[2] = make_int4(rowU[8], rowU[9], rowU[10], rowU[11]);
            dst[3] = make_int4(rowU[12], rowU[13], rowU[14], rowU[15]);
        }
    }

    const int lane = tid & 63;
    const int wave = tid >> 6;
    const int quad = lane >> 4;
    const int l15  = lane & 15;

    // A-frags (BTS ready since barrier 1): A[m=l15][k=quad*8+j]
    f16x8 af[5];
    #pragma unroll
    for (int mt = 0; mt < 5; ++mt)
        af[mt] = *(const f16x8*)(BTS + (mt * 16 + l15) * 32 + quad * 8);
    f16x8 af2[4];
    #pragma unroll
    for (int mt = 0; mt < 4; ++mt)
        af2[mt] = *(const f16x8*)(BTS + (80 + mt * 16 + l15) * 32 + quad * 8);

    __syncthreads();   // im2col + cim ready

    f16x8 bf[4];
    #pragma unroll
    for (int i = 0; i < 4; ++i) {
        int nt = wave + i * 4;
        if (nt < 14)
            bf[i] = *(const f16x8*)(imc + (nt * 16 + l15) * IMS + quad * 8);
    }
    f16x8 bf2 = *(const f16x8*)(cim + (wave * 16 + l15) * IMS + quad * 8);

    __syncthreads();   // all frag loads done -> pool reusable as kvS/qS

    // ---- Phase B2: GEMM1 -> kvS, GEMM2 -> qS ----
    for (int i = 0; i < 4; ++i) {
        int nt = wave + i * 4;
        if (nt >= 14) break;
        int n = nt * 16 + l15;
        bool nvalid = (n < KREG);
        char* rowB = kvS + n * 144;
        #pragma unroll
        for (int mt = 0; mt < 5; ++mt) {
            f32x4 d = __builtin_amdgcn_mfma_f32_16x16x32_f16(
                af[mt], bf[i], (f32x4){0.f, 0.f, 0.f, 0.f}, 0, 0, 0);
            if (mt < 4) {
                if (nvalid) {
                    int2 w2;
                    w2.x = (int)pack_h2(d[0], d[1]);
                    w2.y = (int)pack_h2(d[2], d[3]);
                    *(int2*)(rowB + (mt * 16 + quad * 4) * 2) = w2;
                }
            } else {
                if (nvalid && quad < 2) {   // v channels (BTS rows 64..71)
                    int2 w2;
                    w2.x = (int)pack_h2(d[0], d[1]);
                    w2.y = (int)pack_h2(d[2], d[3]);
                    *(int2*)(rowB + 128 + quad * 8) = w2;
                }
            }
        }
    }
    {
        char* rowQ = qS + (wave * 16 + l15) * 144;
        #pragma unroll
        for (int mt = 0; mt < 4; ++mt) {
            f32x4 d = __builtin_amdgcn_mfma_f32_16x16x32_f16(
                af2[mt], bf2, (f32x4){0.f, 0.f, 0.f, 0.f}, 0, 0, 0);
            int2 w2;
            w2.x = (int)pack_h2(d[0], d[1]);
            w2.y = (int)pack_h2(d[2], d[3]);
            *(int2*)(rowQ + (mt * 16 + quad * 4) * 2) = w2;
        }
    }
    __syncthreads();

    // ---- Phase C: neighborhood attention; a = wave(+4) wave-uniform ----
    const int clz = lane >> 4, cly = (lane >> 2) & 3, clx = lane & 3;
    const int rbase = clz * 36 + cly * 6 + clx;

    float res[2];
    #pragma unroll
    for (int ti = 0; ti < 2; ++ti) {
        int a = wave + ti * 4;                    // wave-uniform
        const int4 qv = *(const int4*)(qS + lane * 144 + a * 16);
        unsigned qp[4] = {(unsigned)qv.x, (unsigned)qv.y,
                          (unsigned)qv.z, (unsigned)qv.w};
        float sim[27];
        float m = -1e30f;
        #pragma unroll
        for (int nn = 0; nn < 27; ++nn) {
            int dz = nn / 9, dy = (nn / 3) % 3, dx = nn % 3;
            int r = rbase + dz * 36 + dy * 6 + dx;
            const int4 kr = *(const int4*)(kvS + (r * 9 + a) * 16);
            float s = dot2((unsigned)kr.x, qp[0],
                      dot2((unsigned)kr.y, qp[1],
                      dot2((unsigned)kr.z, qp[2],
                      dot2((unsigned)kr.w, qp[3], 0.f))));
            sim[nn] = s;
            m = fmaxf(m, s);
        }
        float ssum = 0.f, acc = 0.f;
        #pragma unroll
        for (int nn = 0; nn < 27; ++nn) {
            int dz = nn / 9, dy = (nn / 3) % 3, dx = nn % 3;
            int r = rbase + dz * 36 + dy * 6 + dx;
            const int4 vu = *(const int4*)(kvS + (r * 9 + 8) * 16);
            unsigned hw = ((const unsigned*)&vu)[a >> 1];
            unsigned half = (a & 1) ? (hw >> 16) : (hw & 0xffffu);
            float fv = (float)__builtin_bit_cast(_Float16, (unsigned short)half);
            float e = __expf(sim[nn] - m);
            ssum += e;
            acc = fmaf(e, fv, acc);
        }
        res[ti] = acc / ssum;
    }
    // outP lives in qS row padding (bytes 128..143 of each 144B row)
    *(float*)(qS + lane * 144 + 128 + wave * 4) = fmaxf(res[0], res[1]);
    __syncthreads();

    // ---- max over actions (4 wave-partials) -> fp32 output ----
    if (tid < 64) {
        float4 p = *(const float4*)(qS + tid * 144 + 128);
        float mx = fmaxf(fmaxf(p.x, p.y), fmaxf(p.z, p.w));
        int lz2 = tid >> 4, ly2 = (tid >> 2) & 3, lx2 = tid & 3;
        int o = base_in + (g0z + lz2) * 1024 + (g0y + ly2) * 32 + (g0x + lx2);
        out[o] = mx;
    }
}

extern "C" void kernel_launch(void* const* d_in, const int* in_sizes, int n_in,
                              void* d_out, int out_size, void* d_ws, size_t ws_size,
                              hipStream_t stream) {
    const float* values  = (const float*)d_in[0];
    const float* rewards = (const float*)d_in[1];
    const float* w_qk    = (const float*)d_in[2];
    const float* w_v     = (const float*)d_in[3];
    avi_kernel<<<NB * 512, 256, 0, stream>>>(values, rewards, w_qk, w_v,
                                             (float*)d_out);
}

// Round 9
// 171.856 us; speedup vs baseline: 1.0947x; 1.0947x over previous
//
#include <hip/hip_runtime.h>
#include <hip/hip_bf16.h>

// Problem constants (P=1 folded out everywhere)
#define NB   8      // batch
#define NA   8      // actions
#define ND   8      // dim_qk
#define NCH  64     // NA*ND q/k channels
#define GT   32     // grid T=H=W
#define KREG 216    // 6^3 halo voxels
#define IMS  40     // im2col row stride in halfwords (80 B, 16B-aligned)

typedef _Float16 h2_t  __attribute__((ext_vector_type(2)));
typedef _Float16 f16x8 __attribute__((ext_vector_type(8)));
typedef float    f32x4 __attribute__((ext_vector_type(4)));

static __device__ __forceinline__ unsigned pack_h2(float a, float b) {
#if __has_builtin(__builtin_amdgcn_cvt_pkrtz)
    return __builtin_bit_cast(unsigned, __builtin_amdgcn_cvt_pkrtz(a, b));
#else
    unsigned short ha = __builtin_bit_cast(unsigned short, (_Float16)a);
    unsigned short hb = __builtin_bit_cast(unsigned short, (_Float16)b);
    return (unsigned)ha | ((unsigned)hb << 16);
#endif
}

static __device__ __forceinline__ float dot2(unsigned k, unsigned q, float c) {
#if __has_builtin(__builtin_amdgcn_fdot2)
    return __builtin_amdgcn_fdot2(__builtin_bit_cast(h2_t, k),
                                  __builtin_bit_cast(h2_t, q), c, false);
#else
    h2_t a = __builtin_bit_cast(h2_t, k), b = __builtin_bit_cast(h2_t, q);
    return c + (float)a[0] * (float)b[0] + (float)a[1] * (float)b[1];
#endif
}

// Round-7 verified structure + fused single-pass phase C (no max-subtract:
// |sim| < ~35 stat-bound, exp2 range safe in fp32; see round-9 analysis).
//  A:  stage x (fp32) into xS; build BTS (k rows 0..63 = w_qk[64..127],
//      v rows 64..71 = softmax(w_v), 72..79 zero).
//  B1: im2col fp16 [224][IMS] (OOB voxel columns zeroed).
//  B2: MFMA 16x16x32_f16 -> kvS rows (144 B/vox; units 0..7 k, unit 8 v).
//  C:  q conv fp32 (s_load weights, register-resident — do NOT move to LDS:
//      round-8 showed that spills), q *= log2e, fused 27-neighbor loop:
//      2x k b128 + 1 shared v b128, dot2 sims, exp2, online sum.
__launch_bounds__(256, 4)
__global__ void avi_kernel(const float* __restrict__ values,
                           const float* __restrict__ rewards,
                           const float* __restrict__ w_qk,
                           const float* __restrict__ w_v,
                           float* __restrict__ out) {
    __shared__ __align__(16) float    xS[512];        // 2 KB
    __shared__ __align__(16) _Float16 BTS[80 * 32];   // 5 KB
    __shared__ __align__(16) char     uS[KREG * 144 + 1024];  // 31.4 KB union

    _Float16* imc  = (_Float16*)uS;           // [224][IMS], dead after B2 loads
    char*     kvS  = uS;                      // [216][144B] k/v rows
    float*    outP = (float*)(uS + KREG * 144);

    const int tid  = threadIdx.x;
    const int bb   = blockIdx.x >> 9;      // batch
    const int tile = blockIdx.x & 511;     // 8x8x8 tiles of 4^3
    const int tz = tile >> 6, ty = (tile >> 3) & 7, tx = tile & 7;
    const int g0z = tz * 4, g0y = ty * 4, g0x = tx * 4;
    const int base_in = bb * (GT * GT * GT);

    // ---- Phase A: x staging + BTS build ----
    for (int i = tid; i < 512; i += 256) {
        int lz = i >> 6, ly = (i >> 3) & 7, lx = i & 7;
        int gz = g0z + lz - 2, gy = g0y + ly - 2, gx = g0x + lx - 2;
        float v = 0.f;
        if ((unsigned)gz < 32u && (unsigned)gy < 32u && (unsigned)gx < 32u) {
            int idx = base_in + gz * 1024 + gy * 32 + gx;
            v = values[idx] + rewards[idx];
        }
        xS[i] = v;
    }
    // BTS zero pads (disjoint from fills below)
    for (int i = tid; i < 616; i += 256) {
        int row, col;
        if (i < 400) { row = i / 5; col = 27 + (i % 5); }
        else         { int j = i - 400; row = 72 + j / 27; col = j % 27; }
        BTS[row * 32 + col] = (_Float16)0.f;
    }
    // k rows 0..63 <- w_qk rows 64..127
    for (int i = tid; i < 1728; i += 256) {
        int n = i / 27, k = i - n * 27;
        BTS[n * 32 + k] = (_Float16)w_qk[(NCH + n) * 27 + k];
    }
    // v rows 64..71 <- softmax(w_v)
    if (tid < NA) {
        float r[27], m = -1e30f;
        #pragma unroll
        for (int j = 0; j < 27; ++j) { r[j] = w_v[tid * 27 + j]; m = fmaxf(m, r[j]); }
        float s = 0.f;
        #pragma unroll
        for (int j = 0; j < 27; ++j) { r[j] = __expf(r[j] - m); s += r[j]; }
        float inv = 1.f / s;
        #pragma unroll
        for (int j = 0; j < 27; ++j)
            BTS[(64 + tid) * 32 + j] = (_Float16)(r[j] * inv);
    }
    __syncthreads();

    // ---- Phase B1: im2col fp16 (rows 216..223 zero); mask folded in ----
    if (tid < 224) {
        unsigned rowU[16];
        if (tid < KREG) {
            int vz = tid / 36, rem = tid - vz * 36, vy = rem / 6, vx = rem - vy * 6;
            int gz = g0z + vz - 1, gy = g0y + vy - 1, gx = g0x + vx - 1;
            float mask = ((unsigned)gz < 32u && (unsigned)gy < 32u && (unsigned)gx < 32u)
                             ? 1.f : 0.f;
            float xr[27];
            #pragma unroll
            for (int t = 0; t < 27; ++t) {
                int dz = t / 9, dy = (t / 3) % 3, dx = t % 3;
                xr[t] = xS[(vz + dz) * 64 + (vy + dy) * 8 + (vx + dx)] * mask;
            }
            #pragma unroll
            for (int p = 0; p < 13; ++p) rowU[p] = pack_h2(xr[2 * p], xr[2 * p + 1]);
            rowU[13] = pack_h2(xr[26], 0.f);
            rowU[14] = rowU[15] = 0u;
        } else {
            #pragma unroll
            for (int p = 0; p < 16; ++p) rowU[p] = 0u;
        }
        int4* dst = (int4*)((char*)imc + tid * (IMS * 2));
        dst[0] = make_int4(rowU[0], rowU[1], rowU[2], rowU[3]);
        dst[1] = make_int4(rowU[4], rowU[5], rowU[6], rowU[7]);
        dst[2] = make_int4(rowU[8], rowU[9], rowU[10], rowU[11]);
        dst[3] = make_int4(rowU[12], rowU[13], rowU[14], rowU[15]);
    }

    const int lane = tid & 63;
    const int wave = tid >> 6;
    const int quad = lane >> 4;
    const int l15  = lane & 15;

    // A-frags (weights): A[m=l15][k=quad*8+j] from BTS (ready after barrier 1)
    f16x8 af[5];
    #pragma unroll
    for (int mt = 0; mt < 5; ++mt)
        af[mt] = *(const f16x8*)(BTS + (mt * 16 + l15) * 32 + quad * 8);

    __syncthreads();   // im2col ready

    // B-frags: B[k=quad*8+j][n=l15] = imc[row=n][col=k]; wave's nt tiles
    f16x8 bf[4];
    #pragma unroll
    for (int i = 0; i < 4; ++i) {
        int nt = wave + i * 4;
        if (nt < 14)
            bf[i] = *(const f16x8*)(imc + (nt * 16 + l15) * IMS + quad * 8);
    }

    __syncthreads();   // all frag loads done -> im2col LDS reusable as kvS

    // ---- Phase B2: MFMA + scatter into kvS ----
    for (int i = 0; i < 4; ++i) {
        int nt = wave + i * 4;
        if (nt >= 14) break;
        int n = nt * 16 + l15;
        bool nvalid = (n < KREG);
        char* rowB = kvS + n * 144;
        #pragma unroll
        for (int mt = 0; mt < 5; ++mt) {
            f32x4 d = __builtin_amdgcn_mfma_f32_16x16x32_f16(
                af[mt], bf[i], (f32x4){0.f, 0.f, 0.f, 0.f}, 0, 0, 0);
            // lane's rows: ch = mt*16 + quad*4 + reg
            if (mt < 4) {
                if (nvalid) {
                    int2 w2;
                    w2.x = (int)pack_h2(d[0], d[1]);
                    w2.y = (int)pack_h2(d[2], d[3]);
                    *(int2*)(rowB + (mt * 16 + quad * 4) * 2) = w2;
                }
            } else {
                if (nvalid && quad < 2) {   // v channels (BTS rows 64..71)
                    int2 w2;
                    w2.x = (int)pack_h2(d[0], d[1]);
                    w2.y = (int)pack_h2(d[2], d[3]);
                    *(int2*)(rowB + 128 + quad * 8) = w2;
                }
            }
        }
    }
    __syncthreads();

    // ---- Phase C: fused neighborhood attention, both actions per thread ----
    const int clz = lane >> 4, cly = (lane >> 2) & 3, clx = lane & 3;
    const int rbase = clz * 36 + cly * 6 + clx;

    float xr[27];
    #pragma unroll
    for (int t = 0; t < 27; ++t) {
        int dz = t / 9, dy = (t / 3) % 3, dx = t % 3;
        xr[t] = xS[(clz + 1 + dz) * 64 + (cly + 1 + dy) * 8 + (clx + 1 + dx)];
    }

    // q conv fp32, both actions; fold log2(e) into the pack -> exp2 later
    const float L2E = 1.44269504f;
    unsigned qp0[4], qp1[4];
    #pragma unroll
    for (int ti = 0; ti < 2; ++ti) {
        int a = wave + ti * 4;                    // wave-uniform -> s_load
        const float* wq = w_qk + a * ND * 27;     // q weights: rows 0..63
        float q[ND];
        #pragma unroll
        for (int d = 0; d < ND; ++d) {
            float acc = 0.f;
            #pragma unroll
            for (int t = 0; t < 27; ++t) acc = fmaf(wq[d * 27 + t], xr[t], acc);
            q[d] = acc * L2E;
        }
        unsigned* qp = ti ? qp1 : qp0;
        #pragma unroll
        for (int j = 0; j < 4; ++j) qp[j] = pack_h2(q[2 * j], q[2 * j + 1]);
    }

    const int a0 = wave, a1 = wave + 4;
    const unsigned vsh = (wave & 1) * 16;
    float ssum0 = 0.f, acc0 = 0.f, ssum1 = 0.f, acc1 = 0.f;
    #pragma unroll
    for (int nn = 0; nn < 27; ++nn) {
        int dz = nn / 9, dy = (nn / 3) % 3, dx = nn % 3;
        int r = rbase + dz * 36 + dy * 6 + dx;
        const char* rowB = kvS + r * 144;
        const int4 k0 = *(const int4*)(rowB + a0 * 16);
        const int4 k1 = *(const int4*)(rowB + a1 * 16);
        const int4 vu = *(const int4*)(rowB + 128);
        float s0 = dot2((unsigned)k0.x, qp0[0],
                   dot2((unsigned)k0.y, qp0[1],
                   dot2((unsigned)k0.z, qp0[2],
                   dot2((unsigned)k0.w, qp0[3], 0.f))));
        float s1 = dot2((unsigned)k1.x, qp1[0],
                   dot2((unsigned)k1.y, qp1[1],
                   dot2((unsigned)k1.z, qp1[2],
                   dot2((unsigned)k1.w, qp1[3], 0.f))));
        float e0 = exp2f(s0);
        float e1 = exp2f(s1);
        unsigned hw0 = ((const unsigned*)&vu)[wave >> 1];
        unsigned hw1 = ((const unsigned*)&vu)[(wave >> 1) + 2];
        float v0 = (float)__builtin_bit_cast(_Float16,
                       (unsigned short)((hw0 >> vsh) & 0xffffu));
        float v1 = (float)__builtin_bit_cast(_Float16,
                       (unsigned short)((hw1 >> vsh) & 0xffffu));
        ssum0 += e0; acc0 = fmaf(e0, v0, acc0);
        ssum1 += e1; acc1 = fmaf(e1, v1, acc1);
    }
    float res = fmaxf(acc0 / ssum0, acc1 / ssum1);
    outP[lane * 4 + wave] = res;
    __syncthreads();

    // ---- max over actions (4 wave-partials) -> fp32 output ----
    if (tid < 64) {
        float4 p = *(const float4*)(outP + tid * 4);
        float mx = fmaxf(fmaxf(p.x, p.y), fmaxf(p.z, p.w));
        int lz2 = tid >> 4, ly2 = (tid >> 2) & 3, lx2 = tid & 3;
        int o = base_in + (g0z + lz2) * 1024 + (g0y + ly2) * 32 + (g0x + lx2);
        out[o] = mx;
    }
}

extern "C" void kernel_launch(void* const* d_in, const int* in_sizes, int n_in,
                              void* d_out, int out_size, void* d_ws, size_t ws_size,
                              hipStream_t stream) {
    const float* values  = (const float*)d_in[0];
    const float* rewards = (const float*)d_in[1];
    const float* w_qk    = (const float*)d_in[2];
    const float* w_v     = (const float*)d_in[3];
    avi_kernel<<<NB * 512, 256, 0, stream>>>(values, rewards, w_qk, w_v,
                                             (float*)d_out);
}

// Round 10
// 133.080 us; speedup vs baseline: 1.4137x; 1.2914x over previous
//
#include <hip/hip_runtime.h>
#include <hip/hip_bf16.h>

// Problem constants (P=1 folded out everywhere)
#define NB   8      // batch
#define NA   8      // actions
#define ND   8      // dim_qk
#define NCH  64     // NA*ND q/k channels
#define GT   32     // grid T=H=W
#define KREG 216    // 6^3 halo voxels
#define IMS  40     // im2col row stride in halfwords (80 B, 16B-aligned)

typedef _Float16 h2_t  __attribute__((ext_vector_type(2)));
typedef _Float16 f16x8 __attribute__((ext_vector_type(8)));
typedef float    f32x4 __attribute__((ext_vector_type(4)));

static __device__ __forceinline__ unsigned pack_h2(float a, float b) {
#if __has_builtin(__builtin_amdgcn_cvt_pkrtz)
    return __builtin_bit_cast(unsigned, __builtin_amdgcn_cvt_pkrtz(a, b));
#else
    unsigned short ha = __builtin_bit_cast(unsigned short, (_Float16)a);
    unsigned short hb = __builtin_bit_cast(unsigned short, (_Float16)b);
    return (unsigned)ha | ((unsigned)hb << 16);
#endif
}

static __device__ __forceinline__ float dot2(unsigned k, unsigned q, float c) {
#if __has_builtin(__builtin_amdgcn_fdot2)
    return __builtin_amdgcn_fdot2(__builtin_bit_cast(h2_t, k),
                                  __builtin_bit_cast(h2_t, q), c, false);
#else
    h2_t a = __builtin_bit_cast(h2_t, k), b = __builtin_bit_cast(h2_t, q);
    return c + (float)a[0] * (float)b[0] + (float)a[1] * (float)b[1];
#endif
}

// Round-7 verified skeleton. Phase C is PER-ACTION (round-8/9 lesson: keeping
// both actions' state live spills one VGPR -> 27 scratch round-trips/thread;
// WRITE_SIZE 2->6 MB and +35us stall. Per-action live set fits: xr[27]+qp[4]).
// No softmax max-subtract (validated round 9: |sim|<~35, absmax unchanged).
//  A:  stage x (fp32) into xS; build BTS (k rows 0..63 = w_qk[64..127],
//      v rows 64..71 = softmax(w_v), 72..79 zero).
//  B1: im2col fp16 [224][IMS] (OOB voxel columns zeroed).
//  B2: MFMA 16x16x32_f16 -> kvS rows (144 B/vox; units 0..7 k, unit 8 v).
//  C:  per action: q conv fp32 (s_load weights, register-resident), q*=log2e,
//      single 27-neighbor loop: k b128 + dot2 + exp2 + scalar-u16 v + fma.
__launch_bounds__(256, 4)
__global__ void avi_kernel(const float* __restrict__ values,
                           const float* __restrict__ rewards,
                           const float* __restrict__ w_qk,
                           const float* __restrict__ w_v,
                           float* __restrict__ out) {
    __shared__ __align__(16) float    xS[512];        // 2 KB
    __shared__ __align__(16) _Float16 BTS[80 * 32];   // 5 KB
    __shared__ __align__(16) char     uS[KREG * 144 + 1024];  // 31.4 KB union

    _Float16* imc  = (_Float16*)uS;           // [224][IMS], dead after B2 loads
    char*     kvS  = uS;                      // [216][144B] k/v rows
    float*    outP = (float*)(uS + KREG * 144);

    const int tid  = threadIdx.x;
    const int bb   = blockIdx.x >> 9;      // batch
    const int tile = blockIdx.x & 511;     // 8x8x8 tiles of 4^3
    const int tz = tile >> 6, ty = (tile >> 3) & 7, tx = tile & 7;
    const int g0z = tz * 4, g0y = ty * 4, g0x = tx * 4;
    const int base_in = bb * (GT * GT * GT);

    // ---- Phase A: x staging + BTS build ----
    for (int i = tid; i < 512; i += 256) {
        int lz = i >> 6, ly = (i >> 3) & 7, lx = i & 7;
        int gz = g0z + lz - 2, gy = g0y + ly - 2, gx = g0x + lx - 2;
        float v = 0.f;
        if ((unsigned)gz < 32u && (unsigned)gy < 32u && (unsigned)gx < 32u) {
            int idx = base_in + gz * 1024 + gy * 32 + gx;
            v = values[idx] + rewards[idx];
        }
        xS[i] = v;
    }
    // BTS zero pads (disjoint from fills below)
    for (int i = tid; i < 616; i += 256) {
        int row, col;
        if (i < 400) { row = i / 5; col = 27 + (i % 5); }
        else         { int j = i - 400; row = 72 + j / 27; col = j % 27; }
        BTS[row * 32 + col] = (_Float16)0.f;
    }
    // k rows 0..63 <- w_qk rows 64..127
    for (int i = tid; i < 1728; i += 256) {
        int n = i / 27, k = i - n * 27;
        BTS[n * 32 + k] = (_Float16)w_qk[(NCH + n) * 27 + k];
    }
    // v rows 64..71 <- softmax(w_v)
    if (tid < NA) {
        float r[27], m = -1e30f;
        #pragma unroll
        for (int j = 0; j < 27; ++j) { r[j] = w_v[tid * 27 + j]; m = fmaxf(m, r[j]); }
        float s = 0.f;
        #pragma unroll
        for (int j = 0; j < 27; ++j) { r[j] = __expf(r[j] - m); s += r[j]; }
        float inv = 1.f / s;
        #pragma unroll
        for (int j = 0; j < 27; ++j)
            BTS[(64 + tid) * 32 + j] = (_Float16)(r[j] * inv);
    }
    __syncthreads();

    // ---- Phase B1: im2col fp16 (rows 216..223 zero); mask folded in ----
    if (tid < 224) {
        unsigned rowU[16];
        if (tid < KREG) {
            int vz = tid / 36, rem = tid - vz * 36, vy = rem / 6, vx = rem - vy * 6;
            int gz = g0z + vz - 1, gy = g0y + vy - 1, gx = g0x + vx - 1;
            float mask = ((unsigned)gz < 32u && (unsigned)gy < 32u && (unsigned)gx < 32u)
                             ? 1.f : 0.f;
            float xr[27];
            #pragma unroll
            for (int t = 0; t < 27; ++t) {
                int dz = t / 9, dy = (t / 3) % 3, dx = t % 3;
                xr[t] = xS[(vz + dz) * 64 + (vy + dy) * 8 + (vx + dx)] * mask;
            }
            #pragma unroll
            for (int p = 0; p < 13; ++p) rowU[p] = pack_h2(xr[2 * p], xr[2 * p + 1]);
            rowU[13] = pack_h2(xr[26], 0.f);
            rowU[14] = rowU[15] = 0u;
        } else {
            #pragma unroll
            for (int p = 0; p < 16; ++p) rowU[p] = 0u;
        }
        int4* dst = (int4*)((char*)imc + tid * (IMS * 2));
        dst[0] = make_int4(rowU[0], rowU[1], rowU[2], rowU[3]);
        dst[1] = make_int4(rowU[4], rowU[5], rowU[6], rowU[7]);
        dst[2] = make_int4(rowU[8], rowU[9], rowU[10], rowU[11]);
        dst[3] = make_int4(rowU[12], rowU[13], rowU[14], rowU[15]);
    }

    const int lane = tid & 63;
    const int wave = tid >> 6;
    const int quad = lane >> 4;
    const int l15  = lane & 15;

    // A-frags (weights): A[m=l15][k=quad*8+j] from BTS (ready after barrier 1)
    f16x8 af[5];
    #pragma unroll
    for (int mt = 0; mt < 5; ++mt)
        af[mt] = *(const f16x8*)(BTS + (mt * 16 + l15) * 32 + quad * 8);

    __syncthreads();   // im2col ready

    // B-frags: B[k=quad*8+j][n=l15] = imc[row=n][col=k]; wave's nt tiles
    f16x8 bf[4];
    #pragma unroll
    for (int i = 0; i < 4; ++i) {
        int nt = wave + i * 4;
        if (nt < 14)
            bf[i] = *(const f16x8*)(imc + (nt * 16 + l15) * IMS + quad * 8);
    }

    __syncthreads();   // all frag loads done -> im2col LDS reusable as kvS

    // ---- Phase B2: MFMA + scatter into kvS ----
    for (int i = 0; i < 4; ++i) {
        int nt = wave + i * 4;
        if (nt >= 14) break;
        int n = nt * 16 + l15;
        bool nvalid = (n < KREG);
        char* rowB = kvS + n * 144;
        #pragma unroll
        for (int mt = 0; mt < 5; ++mt) {
            f32x4 d = __builtin_amdgcn_mfma_f32_16x16x32_f16(
                af[mt], bf[i], (f32x4){0.f, 0.f, 0.f, 0.f}, 0, 0, 0);
            // lane's rows: ch = mt*16 + quad*4 + reg
            if (mt < 4) {
                if (nvalid) {
                    int2 w2;
                    w2.x = (int)pack_h2(d[0], d[1]);
                    w2.y = (int)pack_h2(d[2], d[3]);
                    *(int2*)(rowB + (mt * 16 + quad * 4) * 2) = w2;
                }
            } else {
                if (nvalid && quad < 2) {   // v channels (BTS rows 64..71)
                    int2 w2;
                    w2.x = (int)pack_h2(d[0], d[1]);
                    w2.y = (int)pack_h2(d[2], d[3]);
                    *(int2*)(rowB + 128 + quad * 8) = w2;
                }
            }
        }
    }
    __syncthreads();

    // ---- Phase C: per-action fused attention (min live set, no spill) ----
    const int clz = lane >> 4, cly = (lane >> 2) & 3, clx = lane & 3;
    const int rbase = clz * 36 + cly * 6 + clx;

    float xr[27];
    #pragma unroll
    for (int t = 0; t < 27; ++t) {
        int dz = t / 9, dy = (t / 3) % 3, dx = t % 3;
        xr[t] = xS[(clz + 1 + dz) * 64 + (cly + 1 + dy) * 8 + (clx + 1 + dx)];
    }

    const float L2E = 1.44269504f;
    float best = -1e30f;
    #pragma unroll
    for (int ti = 0; ti < 2; ++ti) {
        int a = wave + ti * 4;                    // wave-uniform -> s_load
        const float* wq = w_qk + a * ND * 27;     // q weights: rows 0..63
        float q[ND];
        #pragma unroll
        for (int d = 0; d < ND; ++d) {
            float acc = 0.f;
            #pragma unroll
            for (int t = 0; t < 27; ++t) acc = fmaf(wq[d * 27 + t], xr[t], acc);
            q[d] = acc * L2E;   // fold log2e -> exp2 in the loop
        }
        unsigned qp[4];
        #pragma unroll
        for (int j = 0; j < 4; ++j) qp[j] = pack_h2(q[2 * j], q[2 * j + 1]);

        float ssum = 0.f, acc = 0.f;
        #pragma unroll
        for (int nn = 0; nn < 27; ++nn) {
            int dz = nn / 9, dy = (nn / 3) % 3, dx = nn % 3;
            int r = rbase + dz * 36 + dy * 6 + dx;
            const char* rowB = kvS + r * 144;
            const int4 kr = *(const int4*)(rowB + a * 16);
            float s = dot2((unsigned)kr.x, qp[0],
                      dot2((unsigned)kr.y, qp[1],
                      dot2((unsigned)kr.z, qp[2],
                      dot2((unsigned)kr.w, qp[3], 0.f))));
            float e = exp2f(s);
            float fv = (float)*(const _Float16*)(rowB + 128 + a * 2);
            ssum += e;
            acc = fmaf(e, fv, acc);
        }
        best = fmaxf(best, acc / ssum);
    }
    outP[lane * 4 + wave] = best;
    __syncthreads();

    // ---- max over actions (4 wave-partials) -> fp32 output ----
    if (tid < 64) {
        float4 p = *(const float4*)(outP + tid * 4);
        float mx = fmaxf(fmaxf(p.x, p.y), fmaxf(p.z, p.w));
        int lz2 = tid >> 4, ly2 = (tid >> 2) & 3, lx2 = tid & 3;
        int o = base_in + (g0z + lz2) * 1024 + (g0y + ly2) * 32 + (g0x + lx2);
        out[o] = mx;
    }
}

extern "C" void kernel_launch(void* const* d_in, const int* in_sizes, int n_in,
                              void* d_out, int out_size, void* d_ws, size_t ws_size,
                              hipStream_t stream) {
    const float* values  = (const float*)d_in[0];
    const float* rewards = (const float*)d_in[1];
    const float* w_qk    = (const float*)d_in[2];
    const float* w_v     = (const float*)d_in[3];
    avi_kernel<<<NB * 512, 256, 0, stream>>>(values, rewards, w_qk, w_v,
                                             (float*)d_out);
}

// Round 11
// 132.207 us; speedup vs baseline: 1.4230x; 1.0066x over previous
//
#include <hip/hip_runtime.h>
#include <hip/hip_bf16.h>

// Problem constants (P=1 folded out everywhere)
#define NB   8      // batch
#define NA   8      // actions
#define ND   8      // dim_qk
#define NCH  64     // NA*ND q/k channels
#define GT   32     // grid T=H=W
#define KREG 216    // 6^3 halo voxels
#define IMS  40     // im2col/BTS row stride in halfwords (80 B)

// LDS pool overlays (bytes). kvS aliases BTS+imc (dead after frag loads).
#define XS_OFF   0        // float[512], live A -> phase C
#define BTS_OFF  2048     // [80][IMS] halfs = 6400 B, live A -> af loads
#define IMC_OFF  8448     // [224][IMS] halfs = 17920 B, live B1 -> bf loads
#define KV_OFF   2048     // [216][144B] k rows, live B2 -> C (aliases BTS/imc)
#define VS_OFF   33152    // float[8][216] v plane = 6912 B
#define POOL_SZ  40064    // <= 40960 -> 4 blocks/CU

typedef _Float16 h2_t  __attribute__((ext_vector_type(2)));
typedef _Float16 f16x8 __attribute__((ext_vector_type(8)));
typedef float    f32x4 __attribute__((ext_vector_type(4)));

static __device__ __forceinline__ unsigned pack_h2(float a, float b) {
#if __has_builtin(__builtin_amdgcn_cvt_pkrtz)
    return __builtin_bit_cast(unsigned, __builtin_amdgcn_cvt_pkrtz(a, b));
#else
    unsigned short ha = __builtin_bit_cast(unsigned short, (_Float16)a);
    unsigned short hb = __builtin_bit_cast(unsigned short, (_Float16)b);
    return (unsigned)ha | ((unsigned)hb << 16);
#endif
}

static __device__ __forceinline__ float dot2(unsigned k, unsigned q, float c) {
#if __has_builtin(__builtin_amdgcn_fdot2)
    return __builtin_amdgcn_fdot2(__builtin_bit_cast(h2_t, k),
                                  __builtin_bit_cast(h2_t, q), c, false);
#else
    h2_t a = __builtin_bit_cast(h2_t, k), b = __builtin_bit_cast(h2_t, q);
    return c + (float)a[0] * (float)b[0] + (float)a[1] * (float)b[1];
#endif
}

// Prep: pack the BTS image into ws as u32 halfword-pairs, [80][IMS/2 u32]:
// rows 0..63 = k weights (w_qk rows 64..127), 64..71 = softmax(w_v),
// 72..79 = zero; cols 27..39 zero. Row stride 20 u32 -> af loads 2-way (free).
__global__ void prep_weights(const float* __restrict__ w_qk,
                             const float* __restrict__ w_v,
                             unsigned* __restrict__ ws) {
    int t = threadIdx.x;  // 0..127
    if (t < 64) {
        const float* w = w_qk + (NCH + t) * 27;
        unsigned* dst = ws + t * (IMS / 2);
        float xr[28];
        #pragma unroll
        for (int j = 0; j < 27; ++j) xr[j] = w[j];
        xr[27] = 0.f;
        #pragma unroll
        for (int p = 0; p < 14; ++p) dst[p] = pack_h2(xr[2 * p], xr[2 * p + 1]);
        #pragma unroll
        for (int p = 14; p < 20; ++p) dst[p] = 0u;
    } else if (t < 72) {
        int a = t - 64;
        float r[28], m = -1e30f;
        #pragma unroll
        for (int j = 0; j < 27; ++j) { r[j] = w_v[a * 27 + j]; m = fmaxf(m, r[j]); }
        float s = 0.f;
        #pragma unroll
        for (int j = 0; j < 27; ++j) { r[j] = __expf(r[j] - m); s += r[j]; }
        float inv = 1.f / s;
        #pragma unroll
        for (int j = 0; j < 27; ++j) r[j] *= inv;
        r[27] = 0.f;
        unsigned* dst = ws + (64 + a) * (IMS / 2);
        #pragma unroll
        for (int p = 0; p < 14; ++p) dst[p] = pack_h2(r[2 * p], r[2 * p + 1]);
        #pragma unroll
        for (int p = 14; p < 20; ++p) dst[p] = 0u;
    } else if (t < 80) {
        unsigned* dst = ws + t * (IMS / 2);
        #pragma unroll
        for (int p = 0; p < 20; ++p) dst[p] = 0u;
    }
}

// Main kernel: round-10 verified structure + prep-packed BTS (stride 40),
// fp32 v plane (conflict-free), LDS pool overlays. Per-action phase C
// (round-8/9 lesson: both-actions-live spills); no softmax max-subtract
// (validated round 9).
__launch_bounds__(256, 4)
__global__ void avi_kernel(const float* __restrict__ values,
                           const float* __restrict__ rewards,
                           const float* __restrict__ w_qk,
                           const unsigned* __restrict__ wsBTS,
                           float* __restrict__ out) {
    __shared__ __align__(16) char pool[POOL_SZ];
    float*    xS   = (float*)(pool + XS_OFF);
    _Float16* BTSl = (_Float16*)(pool + BTS_OFF);
    _Float16* imc  = (_Float16*)(pool + IMC_OFF);

    const int tid  = threadIdx.x;
    const int bb   = blockIdx.x >> 9;      // batch
    const int tile = blockIdx.x & 511;     // 8x8x8 tiles of 4^3
    const int tz = tile >> 6, ty = (tile >> 3) & 7, tx = tile & 7;
    const int g0z = tz * 4, g0y = ty * 4, g0x = tx * 4;
    const int base_in = bb * (GT * GT * GT);

    // ---- Phase A: x staging + BTS copy (1600 u32 = 400 int4) ----
    for (int i = tid; i < 512; i += 256) {
        int lz = i >> 6, ly = (i >> 3) & 7, lx = i & 7;
        int gz = g0z + lz - 2, gy = g0y + ly - 2, gx = g0x + lx - 2;
        float v = 0.f;
        if ((unsigned)gz < 32u && (unsigned)gy < 32u && (unsigned)gx < 32u) {
            int idx = base_in + gz * 1024 + gy * 32 + gx;
            v = values[idx] + rewards[idx];
        }
        xS[i] = v;
    }
    for (int i = tid; i < 400; i += 256)
        ((int4*)BTSl)[i] = ((const int4*)wsBTS)[i];
    __syncthreads();

    // ---- Phase B1: im2col fp16 [224][IMS] (OOB voxel columns zeroed) ----
    if (tid < 224) {
        unsigned rowU[16];
        if (tid < KREG) {
            int vz = tid / 36, rem = tid - vz * 36, vy = rem / 6, vx = rem - vy * 6;
            int gz = g0z + vz - 1, gy = g0y + vy - 1, gx = g0x + vx - 1;
            float mask = ((unsigned)gz < 32u && (unsigned)gy < 32u && (unsigned)gx < 32u)
                             ? 1.f : 0.f;
            float xr[27];
            #pragma unroll
            for (int t = 0; t < 27; ++t) {
                int dz = t / 9, dy = (t / 3) % 3, dx = t % 3;
                xr[t] = xS[(vz + dz) * 64 + (vy + dy) * 8 + (vx + dx)] * mask;
            }
            #pragma unroll
            for (int p = 0; p < 13; ++p) rowU[p] = pack_h2(xr[2 * p], xr[2 * p + 1]);
            rowU[13] = pack_h2(xr[26], 0.f);
            rowU[14] = rowU[15] = 0u;
        } else {
            #pragma unroll
            for (int p = 0; p < 16; ++p) rowU[p] = 0u;
        }
        int4* dst = (int4*)((char*)imc + tid * (IMS * 2));
        dst[0] = make_int4(rowU[0], rowU[1], rowU[2], rowU[3]);
        dst[1] = make_int4(rowU[4], rowU[5], rowU[6], rowU[7]);
        dst[2] = make_int4(rowU[8], rowU[9], rowU[10], rowU[11]);
        dst[3] = make_int4(rowU[12], rowU[13], rowU[14], rowU[15]);
    }

    const int lane = tid & 63;
    const int wave = tid >> 6;
    const int quad = lane >> 4;
    const int l15  = lane & 15;

    // A-frags: A[m=l15][k=quad*8+j]; stride 40 halfs -> 2-way (free)
    f16x8 af[5];
    #pragma unroll
    for (int mt = 0; mt < 5; ++mt)
        af[mt] = *(const f16x8*)(BTSl + (mt * 16 + l15) * IMS + quad * 8);

    __syncthreads();   // im2col ready

    f16x8 bf[4];
    #pragma unroll
    for (int i = 0; i < 4; ++i) {
        int nt = wave + i * 4;
        if (nt < 14)
            bf[i] = *(const f16x8*)(imc + (nt * 16 + l15) * IMS + quad * 8);
    }

    __syncthreads();   // frag loads done -> BTS/imc LDS reusable as kvS

    // ---- Phase B2: MFMA; k -> kvS rows (144 B), v -> fp32 vS plane ----
    for (int i = 0; i < 4; ++i) {
        int nt = wave + i * 4;
        if (nt >= 14) break;
        int n = nt * 16 + l15;
        bool nvalid = (n < KREG);
        char* rowB = pool + KV_OFF + n * 144;
        #pragma unroll
        for (int mt = 0; mt < 5; ++mt) {
            f32x4 d = __builtin_amdgcn_mfma_f32_16x16x32_f16(
                af[mt], bf[i], (f32x4){0.f, 0.f, 0.f, 0.f}, 0, 0, 0);
            if (mt < 4) {
                if (nvalid) {
                    int2 w2;
                    w2.x = (int)pack_h2(d[0], d[1]);
                    w2.y = (int)pack_h2(d[2], d[3]);
                    *(int2*)(rowB + (mt * 16 + quad * 4) * 2) = w2;
                }
            } else if (nvalid && quad < 2) {    // v: actions quad*4+reg
                float* vp = (float*)(pool + VS_OFF);
                #pragma unroll
                for (int reg = 0; reg < 4; ++reg)
                    vp[(quad * 4 + reg) * KREG + n] = d[reg];
            }
        }
    }
    __syncthreads();

    // ---- Phase C: per-action fused attention ----
    const int clz = lane >> 4, cly = (lane >> 2) & 3, clx = lane & 3;
    const int rbase = clz * 36 + cly * 6 + clx;

    float xr[27];
    #pragma unroll
    for (int t = 0; t < 27; ++t) {
        int dz = t / 9, dy = (t / 3) % 3, dx = t % 3;
        xr[t] = xS[(clz + 1 + dz) * 64 + (cly + 1 + dy) * 8 + (clx + 1 + dx)];
    }

    const float L2E = 1.44269504f;
    float best = -1e30f;
    #pragma unroll
    for (int ti = 0; ti < 2; ++ti) {
        int a = wave + ti * 4;                    // wave-uniform -> s_load
        const float* wq = w_qk + a * ND * 27;     // q weights: rows 0..63
        float q[ND];
        #pragma unroll
        for (int d = 0; d < ND; ++d) {
            float acc = 0.f;
            #pragma unroll
            for (int t = 0; t < 27; ++t) acc = fmaf(wq[d * 27 + t], xr[t], acc);
            q[d] = acc * L2E;   // fold log2e -> exp2 in the loop
        }
        unsigned qp[4];
        #pragma unroll
        for (int j = 0; j < 4; ++j) qp[j] = pack_h2(q[2 * j], q[2 * j + 1]);

        const float* vplane = (const float*)(pool + VS_OFF) + a * KREG;
        float ssum = 0.f, acc = 0.f;
        #pragma unroll
        for (int nn = 0; nn < 27; ++nn) {
            int dz = nn / 9, dy = (nn / 3) % 3, dx = nn % 3;
            int r = rbase + dz * 36 + dy * 6 + dx;
            const char* rowB = pool + KV_OFF + r * 144;
            const int4 kr = *(const int4*)(rowB + a * 16);
            float s = dot2((unsigned)kr.x, qp[0],
                      dot2((unsigned)kr.y, qp[1],
                      dot2((unsigned)kr.z, qp[2],
                      dot2((unsigned)kr.w, qp[3], 0.f))));
            float e = exp2f(s);
            float fv = vplane[r];
            ssum += e;
            acc = fmaf(e, fv, acc);
        }
        best = fmaxf(best, acc / ssum);
    }
    // outP lives in kvS unit-8 holes (rows 0..63, bytes 128..143)
    *(float*)(pool + KV_OFF + lane * 144 + 128 + wave * 4) = best;
    __syncthreads();

    // ---- max over actions (4 wave-partials) -> fp32 output ----
    if (tid < 64) {
        float4 p = *(const float4*)(pool + KV_OFF + tid * 144 + 128);
        float mx = fmaxf(fmaxf(p.x, p.y), fmaxf(p.z, p.w));
        int lz2 = tid >> 4, ly2 = (tid >> 2) & 3, lx2 = tid & 3;
        int o = base_in + (g0z + lz2) * 1024 + (g0y + ly2) * 32 + (g0x + lx2);
        out[o] = mx;
    }
}

extern "C" void kernel_launch(void* const* d_in, const int* in_sizes, int n_in,
                              void* d_out, int out_size, void* d_ws, size_t ws_size,
                              hipStream_t stream) {
    const float* values  = (const float*)d_in[0];
    const float* rewards = (const float*)d_in[1];
    const float* w_qk    = (const float*)d_in[2];
    const float* w_v     = (const float*)d_in[3];
    unsigned* ws = (unsigned*)d_ws;   // 6400 B used (packed BTS image)

    prep_weights<<<1, 128, 0, stream>>>(w_qk, w_v, ws);
    avi_kernel<<<NB * 512, 256, 0, stream>>>(values, rewards, w_qk, ws,
                                             (float*)d_out);
}

// Round 12
// 109.451 us; speedup vs baseline: 1.7189x; 1.2079x over previous
//
#include <hip/hip_runtime.h>
#include <hip/hip_bf16.h>

// Problem constants (P=1 folded out everywhere)
#define NB   8      // batch
#define NA   8      // actions
#define ND   8      // dim_qk
#define NCH  64     // NA*ND q/k channels
#define GT   32     // grid T=H=W
#define KREG 216    // 6^3 halo voxels
#define IMS  40     // im2col/weight row stride in halfwords (80 B)

// LDS pool overlays (bytes):
//  build window: xS[0,2048) BTS[2048,13568) imc[13568,31488)
//  attn  window: kvS[0,31104) qS[31104,40320)  (all build data dead by then)
#define XS_OFF   0
#define BTS_OFF  2048
#define IMC_OFF  13568
#define KV_OFF   0
#define QS_OFF   31104
#define POOL_SZ  40320    // <= 40960 -> 4 blocks/CU (16 waves, VGPR cap 128)

typedef _Float16 h2_t  __attribute__((ext_vector_type(2)));
typedef _Float16 f16x8 __attribute__((ext_vector_type(8)));
typedef float    f32x4 __attribute__((ext_vector_type(4)));

static __device__ __forceinline__ unsigned pack_h2(float a, float b) {
#if __has_builtin(__builtin_amdgcn_cvt_pkrtz)
    return __builtin_bit_cast(unsigned, __builtin_amdgcn_cvt_pkrtz(a, b));
#else
    unsigned short ha = __builtin_bit_cast(unsigned short, (_Float16)a);
    unsigned short hb = __builtin_bit_cast(unsigned short, (_Float16)b);
    return (unsigned)ha | ((unsigned)hb << 16);
#endif
}

static __device__ __forceinline__ float dot2(unsigned k, unsigned q, float c) {
#if __has_builtin(__builtin_amdgcn_fdot2)
    return __builtin_amdgcn_fdot2(__builtin_bit_cast(h2_t, k),
                                  __builtin_bit_cast(h2_t, q), c, false);
#else
    h2_t a = __builtin_bit_cast(h2_t, k), b = __builtin_bit_cast(h2_t, q);
    return c + (float)a[0] * (float)b[0] + (float)a[1] * (float)b[1];
#endif
}

// Prep: pack the 144-row weight image into ws, [144][IMS/2 u32] fp16 pairs:
// rows 0..63 k (w_qk 64..127), 64..71 softmax(w_v), 72..79 zero,
// 80..143 q (w_qk 0..63 scaled by log2e -> exp2 in phase C). Cols 27.. zero.
__global__ void prep_weights(const float* __restrict__ w_qk,
                             const float* __restrict__ w_v,
                             unsigned* __restrict__ ws) {
    int t = threadIdx.x;  // 0..255, rows 0..143 active
    if (t >= 144) return;
    float r[28];
    r[27] = 0.f;
    if (t < 64) {
        const float* w = w_qk + (NCH + t) * 27;
        #pragma unroll
        for (int j = 0; j < 27; ++j) r[j] = w[j];
    } else if (t < 72) {
        int a = t - 64;
        float m = -1e30f;
        #pragma unroll
        for (int j = 0; j < 27; ++j) { r[j] = w_v[a * 27 + j]; m = fmaxf(m, r[j]); }
        float s = 0.f;
        #pragma unroll
        for (int j = 0; j < 27; ++j) { r[j] = __expf(r[j] - m); s += r[j]; }
        float inv = 1.f / s;
        #pragma unroll
        for (int j = 0; j < 27; ++j) r[j] *= inv;
    } else if (t < 80) {
        #pragma unroll
        for (int j = 0; j < 27; ++j) r[j] = 0.f;
    } else {
        const float* w = w_qk + (t - 80) * 27;
        const float L2E = 1.44269504f;
        #pragma unroll
        for (int j = 0; j < 27; ++j) r[j] = w[j] * L2E;
    }
    unsigned* dst = ws + t * (IMS / 2);
    #pragma unroll
    for (int p = 0; p < 14; ++p) dst[p] = pack_h2(r[2 * p], r[2 * p + 1]);
    #pragma unroll
    for (int p = 14; p < 20; ++p) dst[p] = 0u;
}

// Unified-GEMM kernel: ONE MFMA pass (M=144: k+v+q, shared B-frags — fixes
// round-8's duplicate-path VGPR blowup) computes k,v AND q; phase C is pure
// attention (2 b128 q reads replace 432 scalar FMAs). Per-action phase C
// (round-10 win); no softmax max-subtract (validated round 9).
__launch_bounds__(256, 4)
__global__ void avi_kernel(const float* __restrict__ values,
                           const float* __restrict__ rewards,
                           const unsigned* __restrict__ wsBTS,
                           float* __restrict__ out) {
    __shared__ __align__(16) char pool[POOL_SZ];
    float*    xS   = (float*)(pool + XS_OFF);
    _Float16* BTSl = (_Float16*)(pool + BTS_OFF);
    _Float16* imc  = (_Float16*)(pool + IMC_OFF);
    char*     kvS  = pool + KV_OFF;      // [216][144B]: units 0..7 k, unit 8 v
    char*     qS   = pool + QS_OFF;      // [64][144B]: 8 a x 16B q + 16B hole

    const int tid  = threadIdx.x;
    const int bb   = blockIdx.x >> 9;      // batch
    const int tile = blockIdx.x & 511;     // 8x8x8 tiles of 4^3
    const int tz = tile >> 6, ty = (tile >> 3) & 7, tx = tile & 7;
    const int g0z = tz * 4, g0y = ty * 4, g0x = tx * 4;
    const int base_in = bb * (GT * GT * GT);

    // ---- Phase A: x staging + weight-image copy (720 int4) ----
    for (int i = tid; i < 512; i += 256) {
        int lz = i >> 6, ly = (i >> 3) & 7, lx = i & 7;
        int gz = g0z + lz - 2, gy = g0y + ly - 2, gx = g0x + lx - 2;
        float v = 0.f;
        if ((unsigned)gz < 32u && (unsigned)gy < 32u && (unsigned)gx < 32u) {
            int idx = base_in + gz * 1024 + gy * 32 + gx;
            v = values[idx] + rewards[idx];
        }
        xS[i] = v;
    }
    for (int i = tid; i < 720; i += 256)
        ((int4*)BTSl)[i] = ((const int4*)wsBTS)[i];
    __syncthreads();

    // ---- Phase B1: im2col fp16 [224][IMS] (OOB voxel columns zeroed) ----
    if (tid < 224) {
        unsigned rowU[16];
        if (tid < KREG) {
            int vz = tid / 36, rem = tid - vz * 36, vy = rem / 6, vx = rem - vy * 6;
            int gz = g0z + vz - 1, gy = g0y + vy - 1, gx = g0x + vx - 1;
            float mask = ((unsigned)gz < 32u && (unsigned)gy < 32u && (unsigned)gx < 32u)
                             ? 1.f : 0.f;
            float xr[27];
            #pragma unroll
            for (int t = 0; t < 27; ++t) {
                int dz = t / 9, dy = (t / 3) % 3, dx = t % 3;
                xr[t] = xS[(vz + dz) * 64 + (vy + dy) * 8 + (vx + dx)] * mask;
            }
            #pragma unroll
            for (int p = 0; p < 13; ++p) rowU[p] = pack_h2(xr[2 * p], xr[2 * p + 1]);
            rowU[13] = pack_h2(xr[26], 0.f);
            rowU[14] = rowU[15] = 0u;
        } else {
            #pragma unroll
            for (int p = 0; p < 16; ++p) rowU[p] = 0u;
        }
        int4* dst = (int4*)((char*)imc + tid * (IMS * 2));
        dst[0] = make_int4(rowU[0], rowU[1], rowU[2], rowU[3]);
        dst[1] = make_int4(rowU[4], rowU[5], rowU[6], rowU[7]);
        dst[2] = make_int4(rowU[8], rowU[9], rowU[10], rowU[11]);
        dst[3] = make_int4(rowU[12], rowU[13], rowU[14], rowU[15]);
    }

    const int lane = tid & 63;
    const int wave = tid >> 6;
    const int quad = lane >> 4;
    const int l15  = lane & 15;

    // A-frags: A[m=l15][k=quad*8+j]; stride 40 halfs -> 2-way (free)
    f16x8 af[9];
    #pragma unroll
    for (int mt = 0; mt < 9; ++mt)
        af[mt] = *(const f16x8*)(BTSl + (mt * 16 + l15) * IMS + quad * 8);

    __syncthreads();   // im2col ready

    f16x8 bf[4];
    #pragma unroll
    for (int i = 0; i < 4; ++i) {
        int nt = wave + i * 4;
        if (nt < 14)
            bf[i] = *(const f16x8*)(imc + (nt * 16 + l15) * IMS + quad * 8);
    }

    __syncthreads();   // frag loads done -> build window reusable as kvS/qS

    // ---- Phase B2: unified MFMA; k,v -> kvS rows, q -> qS rows ----
    for (int i = 0; i < 4; ++i) {
        int nt = wave + i * 4;
        if (nt >= 14) break;
        int n = nt * 16 + l15;
        bool nvalid = (n < KREG);
        int vz = n / 36, rm = n - vz * 36, vy = rm / 6, vx = rm - vy * 6;
        bool ctr = ((unsigned)(vz - 1) < 4u) && ((unsigned)(vy - 1) < 4u) &&
                   ((unsigned)(vx - 1) < 4u);
        int cvox = (vz - 1) * 16 + (vy - 1) * 4 + (vx - 1);
        char* rowB = kvS + n * 144;
        char* rowQ = qS + cvox * 144;
        #pragma unroll
        for (int mt = 0; mt < 9; ++mt) {
            f32x4 d = __builtin_amdgcn_mfma_f32_16x16x32_f16(
                af[mt], bf[i], (f32x4){0.f, 0.f, 0.f, 0.f}, 0, 0, 0);
            if (mt < 4) {                       // k ch = mt*16 + quad*4 + reg
                if (nvalid) {
                    int2 w2;
                    w2.x = (int)pack_h2(d[0], d[1]);
                    w2.y = (int)pack_h2(d[2], d[3]);
                    *(int2*)(rowB + (mt * 16 + quad * 4) * 2) = w2;
                }
            } else if (mt == 4) {               // v actions quad*4+reg (quad<2)
                if (nvalid && quad < 2) {
                    int2 w2;
                    w2.x = (int)pack_h2(d[0], d[1]);
                    w2.y = (int)pack_h2(d[2], d[3]);
                    *(int2*)(rowB + 128 + quad * 8) = w2;
                }
            } else {                            // q ch = (mt-5)*16 + quad*4
                if (ctr) {
                    int ch0 = (mt - 5) * 16 + quad * 4;
                    int a = ch0 >> 3, d0 = ch0 & 7;
                    int2 w2;
                    w2.x = (int)pack_h2(d[0], d[1]);
                    w2.y = (int)pack_h2(d[2], d[3]);
                    *(int2*)(rowQ + a * 16 + d0 * 2) = w2;
                }
            }
        }
    }
    __syncthreads();

    // ---- Phase C: per-action attention (q from qS; log2e pre-folded) ----
    const int clz = lane >> 4, cly = (lane >> 2) & 3, clx = lane & 3;
    const int rbase = clz * 36 + cly * 6 + clx;

    float best = -1e30f;
    #pragma unroll
    for (int ti = 0; ti < 2; ++ti) {
        int a = wave + ti * 4;                    // wave-uniform
        const int4 qv = *(const int4*)(qS + lane * 144 + a * 16);
        unsigned qp[4] = {(unsigned)qv.x, (unsigned)qv.y,
                          (unsigned)qv.z, (unsigned)qv.w};
        float ssum = 0.f, acc = 0.f;
        #pragma unroll
        for (int nn = 0; nn < 27; ++nn) {
            int dz = nn / 9, dy = (nn / 3) % 3, dx = nn % 3;
            int r = rbase + dz * 36 + dy * 6 + dx;
            const char* rowB = kvS + r * 144;
            const int4 kr = *(const int4*)(rowB + a * 16);
            float s = dot2((unsigned)kr.x, qp[0],
                      dot2((unsigned)kr.y, qp[1],
                      dot2((unsigned)kr.z, qp[2],
                      dot2((unsigned)kr.w, qp[3], 0.f))));
            float e = exp2f(s);
            float fv = (float)*(const _Float16*)(rowB + 128 + a * 2);
            ssum += e;
            acc = fmaf(e, fv, acc);
        }
        best = fmaxf(best, acc / ssum);
    }
    // result partials live in qS row holes (bytes 128..143)
    *(float*)(qS + lane * 144 + 128 + wave * 4) = best;
    __syncthreads();

    // ---- max over actions (4 wave-partials) -> fp32 output ----
    if (tid < 64) {
        float4 p = *(const float4*)(qS + tid * 144 + 128);
        float mx = fmaxf(fmaxf(p.x, p.y), fmaxf(p.z, p.w));
        int lz2 = tid >> 4, ly2 = (tid >> 2) & 3, lx2 = tid & 3;
        int o = base_in + (g0z + lz2) * 1024 + (g0y + ly2) * 32 + (g0x + lx2);
        out[o] = mx;
    }
}

extern "C" void kernel_launch(void* const* d_in, const int* in_sizes, int n_in,
                              void* d_out, int out_size, void* d_ws, size_t ws_size,
                              hipStream_t stream) {
    const float* values  = (const float*)d_in[0];
    const float* rewards = (const float*)d_in[1];
    const float* w_qk    = (const float*)d_in[2];
    const float* w_v     = (const float*)d_in[3];
    unsigned* ws = (unsigned*)d_ws;   // 11520 B used (packed 144-row image)

    prep_weights<<<1, 256, 0, stream>>>(w_qk, w_v, ws);
    avi_kernel<<<NB * 512, 256, 0, stream>>>(values, rewards, ws,
                                             (float*)d_out);
}